// Round 14
// baseline (1435.684 us; speedup 1.0000x reference)
//
#include <hip/hip_runtime.h>
#include <stdint.h>

#define B_ 8
#define L_ 2048
#define D_ 1024
#define Z_ 128
#define H_ 2048
#define NE_ 16
#define G_ 32
#define MAXPOS_ 2048
#define NMX_ 4224   // D + Z + H + D (u | z | r | hx) = 33 * 128 exactly
#define EPS_ 1e-5f
#define PC_ 2.0f
#define NTILE_ 16            // L/128 q-tiles
#define NPACK_ 136           // 16*17/2 packed causal tiles
#define TILE_ELEMS_ 16384    // 128*128

typedef short bf16x8 __attribute__((ext_vector_type(8)));
typedef short bf16x4 __attribute__((ext_vector_type(4)));
typedef float f32x4 __attribute__((ext_vector_type(4)));

__device__ __forceinline__ float bf2f(uint16_t u) {
  union { uint32_t u; float f; } v; v.u = ((uint32_t)u) << 16; return v.f;
}
__device__ __forceinline__ uint16_t f2bf(float f) {
  union { float f; uint32_t u; } v; v.f = f;
  uint32_t r = (v.u + 0x7FFFu + ((v.u >> 16) & 1u)) >> 16;
  return (uint16_t)r;
}
__device__ __forceinline__ float sigmoidf_(float x) { return 1.f / (1.f + __expf(-x)); }
__device__ __forceinline__ float siluf_(float x) { return x / (1.f + __expf(-x)); }

__device__ __forceinline__ float waveRedSum(float v) {
  #pragma unroll
  for (int m = 32; m; m >>= 1) v += __shfl_xor(v, m, 64);
  return v;
}

// async global->LDS, 16 bytes per lane; lds dst must be waveBase + lane*16
__device__ __forceinline__ void gl2lds(const uint16_t* g, uint16_t* l) {
  __builtin_amdgcn_global_load_lds(
      (const __attribute__((address_space(1))) void*)g,
      (__attribute__((address_space(3))) void*)l, 16, 0, 0);
}

// ---------------- fallback when workspace too small ----------------
__global__ __launch_bounds__(256) void k_fallback(float* __restrict__ out, int n, float wsmb) {
  for (int i = blockIdx.x * 256 + threadIdx.x; i < n; i += gridDim.x * 256)
    out[i] = (i == 0) ? wsmb : 0.f;
}

// ---------------- fp32 -> bf16 conversion (weights) ----------------
__global__ __launch_bounds__(256) void k_f2bf(const float* __restrict__ src,
                                              uint16_t* __restrict__ dst, int n) {
  for (int i = blockIdx.x * 256 + threadIdx.x; i < n; i += gridDim.x * 256)
    dst[i] = f2bf(src[i]);
}

// ---------------- TimestepNorm, parallel 3-phase ----------------
__global__ __launch_bounds__(256) void k_tnsum(const float* __restrict__ x,
                                               float* __restrict__ s1g,
                                               float* __restrict__ s2g) {
  const int bg = blockIdx.x;
  const int b = bg / G_, g = bg % G_;
  const int tid = threadIdx.x;
  const int j = tid & 31;
  const int lsub = tid >> 5;
  #pragma unroll
  for (int i = 0; i < 16; ++i) {
    const int l = blockIdx.y * 128 + i * 8 + lsub;
    float v = x[((size_t)(b * L_ + l)) * D_ + g * 32 + j];
    float a = v, sq = v * v;
    #pragma unroll
    for (int m = 1; m <= 16; m <<= 1) { a += __shfl_xor(a, m, 64); sq += __shfl_xor(sq, m, 64); }
    if (j == 0) { s1g[(size_t)bg * L_ + l] = a; s2g[(size_t)bg * L_ + l] = sq; }
  }
}

__global__ __launch_bounds__(64) void k_tnscan(float* __restrict__ s1g,
                                               float* __restrict__ s2g) {
  const int bg = blockIdx.x;
  const int lane = threadIdx.x;
  #pragma unroll
  for (int pass = 0; pass < 2; ++pass) {
    float* gp = (pass ? s2g : s1g) + (size_t)bg * L_;
    float loc[32];
    const int b0 = lane * 32;
    float tot = 0.f;
    #pragma unroll
    for (int t = 0; t < 32; ++t) { loc[t] = gp[b0 + t]; tot += loc[t]; }
    float incl = tot;
    #pragma unroll
    for (int off = 1; off < 64; off <<= 1) {
      float nv = __shfl_up(incl, off, 64);
      if (lane >= off) incl += nv;
    }
    float run = incl - tot;
    #pragma unroll
    for (int t = 0; t < 32; ++t) { run += loc[t]; gp[b0 + t] = run; }
  }
}

// Writes xn AND xnT (fused transpose via 32x128 LDS tile).
// xnT must NOT alias s1g/s2g (round-9 race); s1g/s2g live in region D.
__global__ __launch_bounds__(256) void k_tnnorm(const float* __restrict__ x,
                                                const float* __restrict__ s1g,
                                                const float* __restrict__ s2g,
                                                const float* __restrict__ pm,
                                                const float* __restrict__ plv,
                                                const float* __restrict__ w,
                                                const float* __restrict__ bias,
                                                uint16_t* __restrict__ xn,
                                                uint16_t* __restrict__ xnT) {
  __shared__ uint16_t xt[32 * 136];
  const int bg = blockIdx.x;
  const int b = bg / G_, g = bg % G_;
  const int tid = threadIdx.x;
  const int j = tid & 31;
  const int lsub = tid >> 5;
  const float pmv = pm[g];
  const float pvv = __expf(plv[g]);
  const float wj = w[g * 32 + j];
  const float bj = bias[g * 32 + j];
  const float pterm = PC_ * (pvv + pmv * pmv);
  #pragma unroll
  for (int i = 0; i < 16; ++i) {
    const int l = blockIdx.y * 128 + i * 8 + lsub;
    const size_t idx = ((size_t)(b * L_ + l)) * D_ + g * 32 + j;
    const float v = x[idx];
    const float cnt = PC_ + 32.f * (float)(l + 1);
    const float mean = (PC_ * pmv + s1g[(size_t)bg * L_ + l]) / cnt;
    const float var = (pterm + s2g[(size_t)bg * L_ + l]) / cnt - mean * mean;
    const uint16_t o = f2bf((v - mean) * rsqrtf(var + EPS_) * wj + bj);
    xn[idx] = o;
    xt[j * 136 + i * 8 + lsub] = o;
  }
  __syncthreads();
  const int row = tid >> 3, ch = tid & 7;
  uint16_t* dst = xnT + ((size_t)(b * D_ + g * 32 + row)) * L_ + blockIdx.y * 128 + ch * 16;
  *(bf16x8*)&dst[0] = *(const bf16x8*)&xt[row * 136 + ch * 16];
  *(bf16x8*)&dst[8] = *(const bf16x8*)&xt[row * 136 + ch * 16 + 8];
}

// ---------------- RMS sumsq directly from mxT (coalesced along l) ----------------
// grid (L/64, B), 256 threads: thread t -> l = l0+(t&63), d-partition t>>6.
__global__ __launch_bounds__(256) void k_mssq(const float* __restrict__ mxT,
                                              float* __restrict__ ssq) {
  __shared__ float r4[4][64];
  const int l0 = blockIdx.x * 64;
  const int b = blockIdx.y;
  const int t = threadIdx.x;
  const int lq = t & 63, dq = t >> 6;
  const float* src = mxT + (size_t)b * D_ * L_ + l0 + lq;
  float acc = 0.f;
  for (int d = dq * 256; d < dq * 256 + 256; ++d) {
    const float v = src[(size_t)d * L_];
    acc += v * v;
  }
  r4[dq][lq] = acc;
  __syncthreads();
  if (t < 64)
    ssq[(size_t)b * L_ + l0 + t] = r4[0][t] + r4[1][t] + r4[2][t] + r4[3][t];
}

// ---------------- fused 64x64 transpose + RMS-scale + bf16: mxT -> mxn ----------------
// src mxT [D][L] f32; dst mxn [(b*L+l)][D] bf16 = f2bf(v * scale[l] * w[d]).
__global__ __launch_bounds__(256) void k_tprms(const float* __restrict__ src,
                                               const float* __restrict__ ssq,
                                               const float* __restrict__ w,
                                               uint16_t* __restrict__ mxn) {
  __shared__ float tile[64 * 65];
  const int b = blockIdx.z;
  const size_t batch = (size_t)D_ * L_ * b;
  const int c0 = blockIdx.x * 64, r0 = blockIdx.y * 64;   // c0: l, r0: d
  const int t = threadIdx.x;
  const int rr = t >> 4;          // 0..15
  const int cc = (t & 15) * 4;    // 0..60
  #pragma unroll
  for (int p = 0; p < 4; ++p) {
    const int row = p * 16 + rr;
    f32x4 v = *(const f32x4*)&src[batch + (size_t)(r0 + row) * L_ + c0 + cc];
    #pragma unroll
    for (int i = 0; i < 4; ++i) tile[(cc + i) * 65 + row] = v[i];
  }
  __syncthreads();
  const f32x4 wv = *(const f32x4*)&w[r0 + cc];
  #pragma unroll
  for (int p = 0; p < 4; ++p) {
    const int crow = p * 16 + rr;            // l offset within tile
    const int l = c0 + crow;
    const float scale = rsqrtf(ssq[(size_t)b * L_ + l] * (1.f / D_) + EPS_);
    bf16x4 o;
    #pragma unroll
    for (int i = 0; i < 4; ++i)
      o[i] = (short)f2bf(tile[crow * 65 + cc + i] * scale * wv[i]);
    *(bf16x4*)&mxn[((size_t)b * L_ + l) * D_ + r0 + cc] = o;
  }
}

// ---------------- MultiHeadEMA via chunked linear recurrence ----------------
// Round-13: coalesced writeback via padded LDS (obuf[64][33]).
// Round-14: __launch_bounds__(64, 4) caps VGPR at 128 (body needs ~110;
// the unconstrained build allocated 256 -> only 8 blocks/CU, 4 serial
// grid rounds, latency exposed).  16 blocks/CU halves the rounds.
__global__ __launch_bounds__(64, 4) void k_ema(const uint16_t* __restrict__ xnT,
                                               const float* __restrict__ delta,
                                               const float* __restrict__ alpha,
                                               const float* __restrict__ beta,
                                               const float* __restrict__ gamma,
                                               const float* __restrict__ omega,
                                               float* __restrict__ mxT) {
  __shared__ float hst[64 * NE_];
  __shared__ float obuf[64 * 33];   // padded: thread c owns row c (stride 33 ≡ 1 mod 32)
  const int bd = blockIdx.x;
  const int d = bd & (D_ - 1);
  const int c = threadIdx.x;

  float q[NE_], pb[NE_], gs[NE_];
  #pragma unroll
  for (int n = 0; n < NE_; ++n) {
    float p = sigmoidf_(delta[d * NE_ + n]);
    float a = sigmoidf_(alpha[d * NE_ + n]);
    q[n] = 1.f - p * a;
    pb[n] = p * beta[d * NE_ + n];
    gs[n] = gamma[d * NE_ + n] * 0.25f;
  }

  const uint16_t* xp = xnT + (size_t)bd * L_ + c * 32;
  bf16x8 xin[4];
  #pragma unroll
  for (int s = 0; s < 4; ++s) xin[s] = *(const bf16x8*)(xp + s * 8);

  float h[NE_];
  #pragma unroll
  for (int n = 0; n < NE_; ++n) h[n] = 0.f;

  #pragma unroll
  for (int k = 0; k < 32; ++k) {
    float xv = bf2f((uint16_t)xin[k >> 3][k & 7]);
    #pragma unroll
    for (int n = 0; n < NE_; ++n) h[n] = fmaf(q[n], h[n], pb[n] * xv);
  }
  #pragma unroll
  for (int n = 0; n < NE_; ++n) hst[c * NE_ + n] = h[n];
  __syncthreads();

  if (c < NE_) {
    float qq = q[c];
    float q32 = qq * qq; q32 *= q32; q32 *= q32; q32 *= q32; q32 *= q32;  // q^32
    float hi = 0.f;
    for (int cc = 0; cc < 64; ++cc) {
      float cur = hst[cc * NE_ + c];
      hst[cc * NE_ + c] = hi;
      hi = fmaf(q32, hi, cur);
    }
  }
  __syncthreads();

  #pragma unroll
  for (int n = 0; n < NE_; ++n) h[n] = hst[c * NE_ + n];
  const float om = omega[d];
  #pragma unroll
  for (int k = 0; k < 32; ++k) {
    float xv = bf2f((uint16_t)xin[k >> 3][k & 7]);
    float accv = 0.f;
    #pragma unroll
    for (int n = 0; n < NE_; ++n) {
      h[n] = fmaf(q[n], h[n], pb[n] * xv);
      accv = fmaf(gs[n], h[n], accv);
    }
    obuf[c * 33 + k] = accv + om * xv;
  }
  __syncthreads();
  // coalesced writeback: 8 x (64 lanes x 16 B contiguous)
  float* op = mxT + (size_t)bd * L_;
  #pragma unroll
  for (int p = 0; p < 8; ++p) {
    const int l = p * 256 + c * 4;
    const int row = l >> 5, col = l & 31;
    f32x4 v;
    #pragma unroll
    for (int i = 0; i < 4; ++i) v[i] = obuf[row * 33 + col + i];
    *(f32x4*)&op[l] = v;
  }
}

// ==================================================================
// 128x128-tile, BK=32, 4-wave, 2-phase prefetch GEMM, 4 blocks/CU.
// (~711 TF on BASE — round-10 structure, unchanged)
// ==================================================================

template <int MODE>
__global__ __launch_bounds__(256, 4) void k_gemm128(
    const uint16_t* __restrict__ A, const uint16_t* __restrict__ Bm,
    int N, int K,
    const float* __restrict__ bias,
    float* __restrict__ outf, uint16_t* __restrict__ outb,
    uint16_t* __restrict__ ubuf,
    uint16_t* __restrict__ rbuf, float* __restrict__ hxbuf,
    const float* __restrict__ x0,
    const float* __restrict__ qkg, const float* __restrict__ qkb,
    uint16_t* __restrict__ qbuf, uint16_t* __restrict__ kbuf) {
  __shared__ uint16_t sm[17408];  // 34.8 KiB: dbuf at 0/8192; epi transit reuses all
  const int t = threadIdx.x;
  const int lane = t & 63, wave = t >> 6;
  const int quad = lane >> 4, r16 = lane & 15;
  const int wm = wave >> 1, wn = wave & 1;
  const int bm = blockIdx.x * 128;
  const int bn = blockIdx.y * 128;

  f32x4 acc[4][4];
  const f32x4 zf = {0.f, 0.f, 0.f, 0.f};
  #pragma unroll
  for (int i = 0; i < 4; ++i)
    #pragma unroll
    for (int j = 0; j < 4; ++j) acc[i][j] = zf;

  const int sgz = (((t & 3) ^ ((t >> 3) & 3)) << 3);
  const uint16_t* gA = A + (size_t)(bm + (t >> 2)) * K + sgz;
  const uint16_t* gB = Bm + (size_t)(bn + (t >> 2)) * K + sgz;
  const size_t qstep = (size_t)64 * K;
  uint16_t* lA = sm + t * 8;
  uint16_t* lB = sm + 4096 + t * 8;

  const int ga = ((quad ^ ((r16 >> 1) & 3)) << 3);
  const int aOff = (wm * 64 + r16) * 32 + ga;
  const int bOff = 4096 + (wn * 64 + r16) * 32 + ga;

#define STAGE(c, kb) do {                                                     \
    gl2lds(gA + (kb), lA + (c) * 8192);                                       \
    gl2lds(gA + qstep + (kb), lA + (c) * 8192 + 2048);                        \
    gl2lds(gB + (kb), lB + (c) * 8192);                                       \
    gl2lds(gB + qstep + (kb), lB + (c) * 8192 + 2048);                        \
  } while (0)

  const int NT = K >> 5;

  STAGE(0, 0);
  __syncthreads();  // vmcnt(0) drain + barrier

  bf16x8 af[4], bfr[4];
  for (int tt = 0; tt < NT; ++tt) {
    const int c = tt & 1;
    const int co = c * 8192;
    if (tt + 1 < NT) STAGE(c ^ 1, (tt + 1) * 32);  // prefetch next tile
    #pragma unroll
    for (int j = 0; j < 4; ++j)
      bfr[j] = *(const bf16x8*)&sm[co + bOff + j * 512];
    #pragma unroll
    for (int i = 0; i < 4; ++i)
      af[i] = *(const bf16x8*)&sm[co + aOff + i * 512];
    #pragma unroll
    for (int i = 0; i < 4; ++i)
      #pragma unroll
      for (int j = 0; j < 4; ++j)
        acc[i][j] = __builtin_amdgcn_mfma_f32_16x16x32_bf16(
            af[i], bfr[j], acc[i][j], 0, 0, 0);
    __syncthreads();  // single vmcnt(0)+barrier per K-tile
  }
#undef STAGE

  // ---- epilogue ----
  if (MODE == 0) {
    #pragma unroll
    for (int i = 0; i < 4; ++i)
      #pragma unroll
      for (int j = 0; j < 4; ++j)
        #pragma unroll
        for (int r = 0; r < 4; ++r) {
          const int hloc = wn * 64 + j * 16 + r16;
          const int lloc = wm * 64 + i * 16 + quad * 4 + r;
          sm[hloc * 136 + lloc] = f2bf(siluf_(acc[i][j][r] + bias[bn + hloc]));
        }
    __syncthreads();
    const int bb = bm >> 11;            // batch index (tile never crosses)
    const int lb = bm & 2047;           // l offset within batch
    uint16_t* vTb = outb + (size_t)bb * H_ * L_;
    #pragma unroll
    for (int p = 0; p < 8; ++p) {
      const int hloc = p * 16 + (t >> 4);
      const int l0 = (t & 15) * 8;
      bf16x8 v = *(const bf16x8*)&sm[hloc * 136 + l0];
      *(bf16x8*)&vTb[(size_t)(bn + hloc) * L_ + lb + l0] = v;
    }
  } else if (MODE == 1) {
    const int rt = bn >> 7;   // 0-7 u | 8 q/k | 9-24 r | 25-32 hx
    if (rt >= 25) {
      #pragma unroll
      for (int i = 0; i < 4; ++i)
        #pragma unroll
        for (int j = 0; j < 4; ++j)
          #pragma unroll
          for (int r = 0; r < 4; ++r) {
            const int row = bm + wm * 64 + i * 16 + quad * 4 + r;
            const int col = bn + wn * 64 + j * 16 + r16;
            hxbuf[(size_t)row * D_ + (col - D_ - Z_ - H_)] = acc[i][j][r] + bias[col];
          }
    } else if (rt == 8) {
      #pragma unroll
      for (int pass = 0; pass < 2; ++pass) {
        #pragma unroll
        for (int i = 0; i < 4; ++i)
          #pragma unroll
          for (int j = 0; j < 4; ++j)
            #pragma unroll
            for (int r = 0; r < 4; ++r) {
              const int rowloc = wm * 64 + i * 16 + quad * 4 + r;
              const int zc = wn * 64 + j * 16 + r16;
              const float zv = siluf_(acc[i][j][r] + bias[D_ + zc]);
              const float o = pass == 0
                  ? (zv * qkg[zc] + qkb[zc]) * 0.08838834764831845f
                  : zv * qkg[Z_ + zc] + qkb[Z_ + zc];
              sm[rowloc * 136 + zc] = f2bf(o);
            }
        __syncthreads();
        uint16_t* dstb = pass == 0 ? qbuf : kbuf;
        #pragma unroll
        for (int p = 0; p < 8; ++p) {
          const int row = p * 16 + (t >> 4);
          const int c0 = (t & 15) * 8;
          bf16x8 v = *(const bf16x8*)&sm[row * 136 + c0];
          *(bf16x8*)&dstb[(size_t)(bm + row) * Z_ + c0] = v;
        }
        __syncthreads();
      }
    } else {
      const bool isU = rt < 8;
      #pragma unroll
      for (int i = 0; i < 4; ++i)
        #pragma unroll
        for (int j = 0; j < 4; ++j)
          #pragma unroll
          for (int r = 0; r < 4; ++r) {
            const int rowloc = wm * 64 + i * 16 + quad * 4 + r;
            const int colloc = wn * 64 + j * 16 + r16;
            const float val = acc[i][j][r] + bias[bn + colloc];
            sm[rowloc * 136 + colloc] = f2bf(isU ? sigmoidf_(val) : siluf_(val));
          }
      __syncthreads();
      #pragma unroll
      for (int p = 0; p < 8; ++p) {
        const int row = p * 16 + (t >> 4);
        const int c0 = (t & 15) * 8;
        bf16x8 v = *(const bf16x8*)&sm[row * 136 + c0];
        if (isU)
          *(bf16x8*)&ubuf[(size_t)(bm + row) * D_ + bn + c0] = v;
        else
          *(bf16x8*)&rbuf[(size_t)(bm + row) * H_ + (bn - D_ - Z_) + c0] = v;
      }
    }
  } else {
    #pragma unroll
    for (int i = 0; i < 4; ++i) {
      #pragma unroll
      for (int j = 0; j < 4; ++j) {
        #pragma unroll
        for (int r = 0; r < 4; ++r) {
          const int row = bm + wm * 64 + i * 16 + quad * 4 + r;
          const int col = bn + wn * 64 + j * 16 + r16;
          const size_t idx = (size_t)row * N + col;
          float g = siluf_(acc[i][j][r] + hxbuf[idx]);   // read hx (d_out) ...
          float xv = x0[idx];
          outf[idx] = xv + bf2f(ubuf[idx]) * (g - xv);  // ... then write same addr
        }
      }
    }
  }
}

// ---- fused QK^T + rel_bias + causal softmax -> packed-triangular P (bf16) ----
// K/relwin staging double-buffered with prefetch (1 barrier/kt).
__global__ __launch_bounds__(256) void k_qksm(
    const uint16_t* __restrict__ qg, const uint16_t* __restrict__ kg,
    const float* __restrict__ relb, uint16_t* __restrict__ Pp) {
  __shared__ uint16_t Ks[2 * 16384];
  __shared__ float relwin[2 * 256];
  const int qt = blockIdx.x;
  const int bl = blockIdx.y;
  const int tid = threadIdx.x;
  const int w = tid >> 6, lane = tid & 63;
  const int quad = lane >> 4, r16 = lane & 15;
  const uint16_t* qb_b = qg + (size_t)bl * L_ * Z_;
  const uint16_t* kb_b = kg + (size_t)bl * L_ * Z_;
  uint16_t* P_b = Pp + (size_t)bl * NPACK_ * TILE_ELEMS_;

  const int ksg = (tid >> 4) * 128 + (((tid & 15) ^ ((tid >> 4) & 7)) << 3);
  const int kg7 = r16 & 7;

#define STGK(c, kt) do {                                                      \
    const uint16_t* src_ = kb_b + (size_t)(kt) * 128 * Z_;                    \
    _Pragma("unroll")                                                         \
    for (int s2 = 0; s2 < 8; ++s2)                                            \
      gl2lds(src_ + s2 * 2048 + ksg, Ks + (c) * 16384 + s2 * 2048 + tid * 8); \
    if (tid < 255)                                                            \
      relwin[(c) * 256 + tid] = relb[2047 + ((kt) - qt) * 128 - 127 + tid];   \
  } while (0)

  bf16x8 aq[2][4];
  #pragma unroll
  for (int i = 0; i < 2; ++i)
    #pragma unroll
    for (int s = 0; s < 4; ++s)
      aq[i][s] = *(const bf16x8*)&qb_b[(size_t)(qt * 128 + w * 32 + i * 16 + r16) * Z_ +
                                       s * 32 + quad * 8];

  float m8[8], l8[8];
  #pragma unroll
  for (int t = 0; t < 8; ++t) { m8[t] = -3.4e38f; l8[t] = 0.f; }

  const f32x4 zf = {0.f, 0.f, 0.f, 0.f};

  // ---- phase 1: stats ----
  STGK(0, 0);
  __syncthreads();
  for (int kt = 0; kt <= qt; ++kt) {
    const int cur = kt & 1;
    if (kt < qt) STGK(cur ^ 1, kt + 1);
    const uint16_t* Kc = Ks + cur * 16384;
    const float* rw = relwin + cur * 256;
    #pragma unroll
    for (int j = 0; j < 8; ++j) {
      f32x4 a0 = zf, a1 = zf;
      #pragma unroll
      for (int s = 0; s < 4; ++s) {
        bf16x8 bk = *(const bf16x8*)&Kc[(j * 16 + r16) * 128 +
                                        (((s * 4 + quad) ^ kg7) << 3)];
        a0 = __builtin_amdgcn_mfma_f32_16x16x32_bf16(aq[0][s], bk, a0, 0, 0, 0);
        a1 = __builtin_amdgcn_mfma_f32_16x16x32_bf16(aq[1][s], bk, a1, 0, 0, 0);
      }
      #pragma unroll
      for (int i = 0; i < 2; ++i) {
        const f32x4 av = i ? a1 : a0;
        #pragma unroll
        for (int r = 0; r < 4; ++r) {
          const int rloc = w * 32 + i * 16 + quad * 4 + r;
          const int cloc = j * 16 + r16;
          if (kt < qt || cloc <= rloc) {
            const float v = av[r] + rw[cloc - rloc + 127];
            const int t = i * 4 + r;
            const float mn = fmaxf(m8[t], v);
            l8[t] = l8[t] * __expf(m8[t] - mn) + __expf(v - mn);
            m8[t] = mn;
          }
        }
      }
    }
    __syncthreads();
  }

  #pragma unroll
  for (int t = 0; t < 8; ++t) {
    #pragma unroll
    for (int msk = 1; msk <= 8; msk <<= 1) {
      const float mo = __shfl_xor(m8[t], msk, 64);
      const float lo = __shfl_xor(l8[t], msk, 64);
      const float mn = fmaxf(m8[t], mo);
      l8[t] = l8[t] * __expf(m8[t] - mn) + lo * __expf(mo - mn);
      m8[t] = mn;
    }
    l8[t] = 1.f / l8[t];
  }

  // ---- phase 2: recompute, normalize, write packed P ----
  STGK(0, 0);
  __syncthreads();
  for (int kt = 0; kt <= qt; ++kt) {
    const int cur = kt & 1;
    if (kt < qt) STGK(cur ^ 1, kt + 1);
    const uint16_t* Kc = Ks + cur * 16384;
    const float* rw = relwin + cur * 256;
    uint16_t* Pt = P_b + (size_t)(qt * (qt + 1) / 2 + kt) * TILE_ELEMS_;
    #pragma unroll
    for (int j = 0; j < 8; ++j) {
      f32x4 a0 = zf, a1 = zf;
      #pragma unroll
      for (int s = 0; s < 4; ++s) {
        bf16x8 bk = *(const bf16x8*)&Kc[(j * 16 + r16) * 128 +
                                        (((s * 4 + quad) ^ kg7) << 3)];
        a0 = __builtin_amdgcn_mfma_f32_16x16x32_bf16(aq[0][s], bk, a0, 0, 0, 0);
        a1 = __builtin_amdgcn_mfma_f32_16x16x32_bf16(aq[1][s], bk, a1, 0, 0, 0);
      }
      #pragma unroll
      for (int i = 0; i < 2; ++i) {
        const f32x4 av = i ? a1 : a0;
        #pragma unroll
        for (int r = 0; r < 4; ++r) {
          const int rloc = w * 32 + i * 16 + quad * 4 + r;
          const int cloc = j * 16 + r16;
          const int t = i * 4 + r;
          float p = 0.f;
          if (kt < qt || cloc <= rloc) {
            const float v = av[r] + rw[cloc - rloc + 127];
            p = __expf(v - m8[t]) * l8[t];
          }
          Pt[rloc * 128 + cloc] = f2bf(p);
        }
      }
    }
    __syncthreads();
  }
#undef STGK
}

// ---- PV GEMM: hr = (P @ V) * r, packed-triangular P, in-place over r ----
// 128x256 tile, 8 waves, BK=32 dbuf prefetch, 48 KiB LDS, (512,4).
__global__ __launch_bounds__(512, 4) void k_pv(
    const uint16_t* __restrict__ Pp, const uint16_t* __restrict__ vT,
    uint16_t* __restrict__ rh) {
  __shared__ uint16_t sm[24576];  // 48 KiB: buf c at c*12288; A(4096) +0, B(8192) +4096
  const int qt = NTILE_ - 1 - blockIdx.x;   // heavy blocks first
  const int bn = blockIdx.y * 256;
  const int bl = blockIdx.z;
  const uint16_t* Pq = Pp + (size_t)bl * NPACK_ * TILE_ELEMS_ +
                       (size_t)(qt * (qt + 1) / 2) * TILE_ELEMS_;
  const uint16_t* v_b = vT + (size_t)bl * H_ * L_;
  uint16_t* rh_b = rh + (size_t)bl * L_ * H_;

  const int tid = threadIdx.x;
  const int wave = tid >> 6, lane = tid & 63;
  const int quad = lane >> 4, r16 = lane & 15;
  const int wm = wave >> 2, wn = wave & 3;
  const int rowW = wm * 64, colW = wn * 64;

  f32x4 acc[4][4];
  const f32x4 zf = {0.f, 0.f, 0.f, 0.f};
  #pragma unroll
  for (int i = 0; i < 4; ++i)
    #pragma unroll
    for (int j = 0; j < 4; ++j) acc[i][j] = zf;

  const int rA = tid >> 2;   // 0..127
  const int sg = (((tid & 3) ^ ((tid >> 3) & 3)) << 3);
  const int gpv = ((quad ^ ((r16 >> 1) & 3)) << 3);

#define PVSTAGE(c, s) do {                                                    \
    const int kt_ = (s) >> 2, ks_ = (s) & 3;                                  \
    gl2lds(Pq + (size_t)kt_ * TILE_ELEMS_ + rA * 128 + ks_ * 32 + sg,         \
           sm + (c) * 12288 + tid * 8);                                       \
    const uint16_t* Bt_ = v_b + (size_t)(bn + rA) * L_ + kt_ * 128 +          \
                          ks_ * 32 + sg;                                      \
    gl2lds(Bt_, sm + (c) * 12288 + 4096 + tid * 8);                           \
    gl2lds(Bt_ + (size_t)128 * L_, sm + (c) * 12288 + 8192 + tid * 8);        \
  } while (0)

  const int S = 4 * (qt + 1);

  PVSTAGE(0, 0);
  __syncthreads();

  bf16x8 af[4], bfr[4];
  for (int s = 0; s < S; ++s) {
    const int c = s & 1;
    const int co = c * 12288;
    if (s + 1 < S) PVSTAGE(c ^ 1, s + 1);
    #pragma unroll
    for (int j = 0; j < 4; ++j)
      bfr[j] = *(const bf16x8*)&sm[co + 4096 + (colW + j * 16 + r16) * 32 + gpv];
    #pragma unroll
    for (int i = 0; i < 4; ++i)
      af[i] = *(const bf16x8*)&sm[co + (rowW + i * 16 + r16) * 32 + gpv];
    #pragma unroll
    for (int i = 0; i < 4; ++i)
      #pragma unroll
      for (int j = 0; j < 4; ++j)
        acc[i][j] = __builtin_amdgcn_mfma_f32_16x16x32_bf16(af[i], bfr[j], acc[i][j], 0, 0, 0);
    __syncthreads();
  }
#undef PVSTAGE

  #pragma unroll
  for (int i = 0; i < 4; ++i) {
    #pragma unroll
    for (int j = 0; j < 4; ++j) {
      #pragma unroll
      for (int r = 0; r < 4; ++r) {
        const int row = qt * 128 + rowW + i * 16 + quad * 4 + r;
        const int col = bn + colW + j * 16 + r16;
        const size_t idx = (size_t)row * H_ + col;
        const float rv = bf2f(rh_b[idx]);
        rh_b[idx] = f2bf(acc[i][j][r] * rv);
      }
    }
  }
}

extern "C" void kernel_launch(void* const* d_in, const int* in_sizes, int n_in,
                              void* d_out, int out_size, void* d_ws, size_t ws_size,
                              hipStream_t stream) {
  (void)in_sizes; (void)n_in;
  const float* x         = (const float*)d_in[0];
  const float* prior_mean= (const float*)d_in[1];
  const float* prior_logv= (const float*)d_in[2];
  const float* tn_w      = (const float*)d_in[3];
  const float* tn_b      = (const float*)d_in[4];
  const float* delta     = (const float*)d_in[5];
  const float* alpha     = (const float*)d_in[6];
  const float* ema_beta  = (const float*)d_in[7];
  const float* ema_gamma = (const float*)d_in[8];
  const float* omega     = (const float*)d_in[9];
  const float* rms_w     = (const float*)d_in[10];
  const float* Wv        = (const float*)d_in[11];
  const float* bv        = (const float*)d_in[12];
  const float* Wmx       = (const float*)d_in[13];
  const float* bmx       = (const float*)d_in[14];
  const float* Wh        = (const float*)d_in[15];
  const float* qk_gamma  = (const float*)d_in[16];
  const float* qk_beta   = (const float*)d_in[17];
  const float* rel_bias  = (const float*)d_in[18];
  float* out = (float*)d_out;

  const int BL = B_ * L_;
  const size_t MB = 1024 * 1024;
  const size_t REQUIRED = 256 * MB;

  if (ws_size < REQUIRED) {
    k_fallback<<<dim3(4096), dim3(256), 0, stream>>>(out, out_size, (float)(ws_size / MB));
    return;
  }

  char* p = (char*)d_ws;
  // A [0,32): xn (bf16) -> ubuf (bf16)
  uint16_t* xn   = (uint16_t*)(p);
  uint16_t* ubuf = (uint16_t*)(p);
  // B [32,64): xnT (live steps 2-4) -> mxn (live 5-7)
  uint16_t* xnT  = (uint16_t*)(p + 32 * MB);
  uint16_t* mxn  = (uint16_t*)(p + 32 * MB);
  // C [64,128): vT (64 MiB exactly; written by V GEMM, read by k_pv)
  uint16_t* vT   = (uint16_t*)(p + 64 * MB);
  // D [128,192): wv_b [128,132) steps 1-3 | s1g/s2g [132,136) step 2 |
  //              ssq [136,137) step 5 | rbuf/hr (7-11, from 128)
  uint16_t* wv_b = (uint16_t*)(p + 128 * MB);
  float*    s1g  = (float*)   (p + 132 * MB);
  float*    s2g  = (float*)   (p + 134 * MB);
  float*    ssq  = (float*)   (p + 136 * MB);
  uint16_t* rbuf = (uint16_t*)(p + 128 * MB);
  // E [192,256): wmx_b(8.25) | qb(4) | kb(4) | Ppack(35.65)
  uint16_t* wmx_b = (uint16_t*)(p + 192 * MB);
  uint16_t* wh_b  = (uint16_t*)(p + 192 * MB);
  uint16_t* qb    = (uint16_t*)(p + 209 * MB);
  uint16_t* kb2   = (uint16_t*)(p + 213 * MB);
  uint16_t* Ppack = (uint16_t*)(p + 217 * MB);
  // d_out doubles as: mxT f32 (EMA out) -> hx f32 (BASE out) -> out
  float* mxT = out;
  float* hx  = out;

  // 1. weights -> bf16
  k_f2bf<<<dim3(1024), dim3(256), 0, stream>>>(Wv, wv_b, H_ * D_);
  k_f2bf<<<dim3(2048), dim3(256), 0, stream>>>(Wmx, wmx_b, NMX_ * D_);
  // 2. timestep norm (3-phase parallel) -> xn AND xnT (fused transpose)
  k_tnsum<<<dim3(B_ * G_, 16), dim3(256), 0, stream>>>(x, s1g, s2g);
  k_tnscan<<<dim3(B_ * G_), dim3(64), 0, stream>>>(s1g, s2g);
  k_tnnorm<<<dim3(B_ * G_, 16), dim3(256), 0, stream>>>(
      x, s1g, s2g, prior_mean, prior_logv, tn_w, tn_b, xn, xnT);
  // 3. v = silu(xn @ Wv^T + bv), written TRANSPOSED -> vT (C)
  k_gemm128<0><<<dim3(BL / 128, H_ / 128), dim3(256), 0, stream>>>(
      xn, wv_b, H_, D_, bv, nullptr, vT,
      nullptr, nullptr, nullptr, nullptr, nullptr, nullptr, nullptr, nullptr);
  // 4. EMA: xnT -> mxT (d_out), coalesced writeback, 128-VGPR cap
  k_ema<<<dim3(B_ * D_), dim3(64), 0, stream>>>(xnT, delta, alpha, ema_beta, ema_gamma, omega, mxT);
  // 5. RMS directly from mxT: sumsq, then fused transpose+scale -> mxn
  k_mssq<<<dim3(L_ / 64, B_), dim3(256), 0, stream>>>(mxT, ssq);
  k_tprms<<<dim3(L_ / 64, D_ / 64, B_), dim3(256), 0, stream>>>(mxT, ssq, rms_w, mxn);
  // 7. BASE GEMM -> u(A), q/k(E, fused qkprep), r(D), hx(d_out)
  k_gemm128<1><<<dim3(BL / 128, NMX_ / 128), dim3(256), 0, stream>>>(
      mxn, wmx_b, NMX_, D_, bmx, nullptr, nullptr,
      ubuf, rbuf, hx, nullptr, qk_gamma, qk_beta, qb, kb2);
  // 8. fused QK+softmax -> packed P (all 8 batches, one dispatch)
  k_qksm<<<dim3(NTILE_, B_), dim3(256), 0, stream>>>(qb, kb2, rel_bias, Ppack);
  // 9. PV GEMM, hr = (P@V)*r in-place over rbuf (one dispatch)
  k_pv<<<dim3(NTILE_, H_ / 256, B_), dim3(512), 0, stream>>>(Ppack, vT, rbuf);
  // 10. Wh -> bf16 (over dead wmx_b)
  k_f2bf<<<dim3(1024), dim3(256), 0, stream>>>(Wh, wh_b, D_ * H_);
  // 11. final: g = silu(hx + hr@Wh^T); out = x + u*(g-x)
  k_gemm128<4><<<dim3(BL / 128, D_ / 128), dim3(256), 0, stream>>>(
      rbuf, wh_b, D_, H_, nullptr, out, nullptr,
      ubuf, nullptr, hx, x, nullptr, nullptr, nullptr, nullptr);
}

// Round 15
// 1083.648 us; speedup vs baseline: 1.3249x; 1.3249x over previous
//
#include <hip/hip_runtime.h>
#include <stdint.h>

#define B_ 8
#define L_ 2048
#define D_ 1024
#define Z_ 128
#define H_ 2048
#define NE_ 16
#define G_ 32
#define MAXPOS_ 2048
#define NMX_ 4224   // D + Z + H + D (u | z | r | hx) = 33 * 128 exactly
#define EPS_ 1e-5f
#define PC_ 2.0f
#define NTILE_ 16            // L/128 q-tiles
#define NPACK_ 136           // 16*17/2 packed causal tiles
#define TILE_ELEMS_ 16384    // 128*128

typedef short bf16x8 __attribute__((ext_vector_type(8)));
typedef short bf16x4 __attribute__((ext_vector_type(4)));
typedef float f32x4 __attribute__((ext_vector_type(4)));

__device__ __forceinline__ float bf2f(uint16_t u) {
  union { uint32_t u; float f; } v; v.u = ((uint32_t)u) << 16; return v.f;
}
__device__ __forceinline__ uint16_t f2bf(float f) {
  union { float f; uint32_t u; } v; v.f = f;
  uint32_t r = (v.u + 0x7FFFu + ((v.u >> 16) & 1u)) >> 16;
  return (uint16_t)r;
}
__device__ __forceinline__ float sigmoidf_(float x) { return 1.f / (1.f + __expf(-x)); }
__device__ __forceinline__ float siluf_(float x) { return x / (1.f + __expf(-x)); }

__device__ __forceinline__ float waveRedSum(float v) {
  #pragma unroll
  for (int m = 32; m; m >>= 1) v += __shfl_xor(v, m, 64);
  return v;
}

// async global->LDS, 16 bytes per lane; lds dst must be waveBase + lane*16
__device__ __forceinline__ void gl2lds(const uint16_t* g, uint16_t* l) {
  __builtin_amdgcn_global_load_lds(
      (const __attribute__((address_space(1))) void*)g,
      (__attribute__((address_space(3))) void*)l, 16, 0, 0);
}

// ---------------- fallback when workspace too small ----------------
__global__ __launch_bounds__(256) void k_fallback(float* __restrict__ out, int n, float wsmb) {
  for (int i = blockIdx.x * 256 + threadIdx.x; i < n; i += gridDim.x * 256)
    out[i] = (i == 0) ? wsmb : 0.f;
}

// ---------------- fp32 -> bf16 conversion (weights) ----------------
__global__ __launch_bounds__(256) void k_f2bf(const float* __restrict__ src,
                                              uint16_t* __restrict__ dst, int n) {
  for (int i = blockIdx.x * 256 + threadIdx.x; i < n; i += gridDim.x * 256)
    dst[i] = f2bf(src[i]);
}

// ---------------- TimestepNorm, parallel 3-phase ----------------
__global__ __launch_bounds__(256) void k_tnsum(const float* __restrict__ x,
                                               float* __restrict__ s1g,
                                               float* __restrict__ s2g) {
  const int bg = blockIdx.x;
  const int b = bg / G_, g = bg % G_;
  const int tid = threadIdx.x;
  const int j = tid & 31;
  const int lsub = tid >> 5;
  #pragma unroll
  for (int i = 0; i < 16; ++i) {
    const int l = blockIdx.y * 128 + i * 8 + lsub;
    float v = x[((size_t)(b * L_ + l)) * D_ + g * 32 + j];
    float a = v, sq = v * v;
    #pragma unroll
    for (int m = 1; m <= 16; m <<= 1) { a += __shfl_xor(a, m, 64); sq += __shfl_xor(sq, m, 64); }
    if (j == 0) { s1g[(size_t)bg * L_ + l] = a; s2g[(size_t)bg * L_ + l] = sq; }
  }
}

__global__ __launch_bounds__(64) void k_tnscan(float* __restrict__ s1g,
                                               float* __restrict__ s2g) {
  const int bg = blockIdx.x;
  const int lane = threadIdx.x;
  #pragma unroll
  for (int pass = 0; pass < 2; ++pass) {
    float* gp = (pass ? s2g : s1g) + (size_t)bg * L_;
    float loc[32];
    const int b0 = lane * 32;
    float tot = 0.f;
    #pragma unroll
    for (int t = 0; t < 32; ++t) { loc[t] = gp[b0 + t]; tot += loc[t]; }
    float incl = tot;
    #pragma unroll
    for (int off = 1; off < 64; off <<= 1) {
      float nv = __shfl_up(incl, off, 64);
      if (lane >= off) incl += nv;
    }
    float run = incl - tot;
    #pragma unroll
    for (int t = 0; t < 32; ++t) { run += loc[t]; gp[b0 + t] = run; }
  }
}

// Writes xn AND xnT (fused transpose via 32x128 LDS tile).
// xnT must NOT alias s1g/s2g (round-9 race); s1g/s2g live in region D.
__global__ __launch_bounds__(256) void k_tnnorm(const float* __restrict__ x,
                                                const float* __restrict__ s1g,
                                                const float* __restrict__ s2g,
                                                const float* __restrict__ pm,
                                                const float* __restrict__ plv,
                                                const float* __restrict__ w,
                                                const float* __restrict__ bias,
                                                uint16_t* __restrict__ xn,
                                                uint16_t* __restrict__ xnT) {
  __shared__ uint16_t xt[32 * 136];
  const int bg = blockIdx.x;
  const int b = bg / G_, g = bg % G_;
  const int tid = threadIdx.x;
  const int j = tid & 31;
  const int lsub = tid >> 5;
  const float pmv = pm[g];
  const float pvv = __expf(plv[g]);
  const float wj = w[g * 32 + j];
  const float bj = bias[g * 32 + j];
  const float pterm = PC_ * (pvv + pmv * pmv);
  #pragma unroll
  for (int i = 0; i < 16; ++i) {
    const int l = blockIdx.y * 128 + i * 8 + lsub;
    const size_t idx = ((size_t)(b * L_ + l)) * D_ + g * 32 + j;
    const float v = x[idx];
    const float cnt = PC_ + 32.f * (float)(l + 1);
    const float mean = (PC_ * pmv + s1g[(size_t)bg * L_ + l]) / cnt;
    const float var = (pterm + s2g[(size_t)bg * L_ + l]) / cnt - mean * mean;
    const uint16_t o = f2bf((v - mean) * rsqrtf(var + EPS_) * wj + bj);
    xn[idx] = o;
    xt[j * 136 + i * 8 + lsub] = o;
  }
  __syncthreads();
  const int row = tid >> 3, ch = tid & 7;
  uint16_t* dst = xnT + ((size_t)(b * D_ + g * 32 + row)) * L_ + blockIdx.y * 128 + ch * 16;
  *(bf16x8*)&dst[0] = *(const bf16x8*)&xt[row * 136 + ch * 16];
  *(bf16x8*)&dst[8] = *(const bf16x8*)&xt[row * 136 + ch * 16 + 8];
}

// ---------------- RMS sumsq directly from mxT (coalesced along l) ----------------
// grid (L/64, B), 256 threads: thread t -> l = l0+(t&63), d-partition t>>6.
__global__ __launch_bounds__(256) void k_mssq(const float* __restrict__ mxT,
                                              float* __restrict__ ssq) {
  __shared__ float r4[4][64];
  const int l0 = blockIdx.x * 64;
  const int b = blockIdx.y;
  const int t = threadIdx.x;
  const int lq = t & 63, dq = t >> 6;
  const float* src = mxT + (size_t)b * D_ * L_ + l0 + lq;
  float acc = 0.f;
  for (int d = dq * 256; d < dq * 256 + 256; ++d) {
    const float v = src[(size_t)d * L_];
    acc += v * v;
  }
  r4[dq][lq] = acc;
  __syncthreads();
  if (t < 64)
    ssq[(size_t)b * L_ + l0 + t] = r4[0][t] + r4[1][t] + r4[2][t] + r4[3][t];
}

// ---------------- fused 64x64 transpose + RMS-scale + bf16: mxT -> mxn ----------------
// src mxT [D][L] f32; dst mxn [(b*L+l)][D] bf16 = f2bf(v * scale[l] * w[d]).
__global__ __launch_bounds__(256) void k_tprms(const float* __restrict__ src,
                                               const float* __restrict__ ssq,
                                               const float* __restrict__ w,
                                               uint16_t* __restrict__ mxn) {
  __shared__ float tile[64 * 65];
  const int b = blockIdx.z;
  const size_t batch = (size_t)D_ * L_ * b;
  const int c0 = blockIdx.x * 64, r0 = blockIdx.y * 64;   // c0: l, r0: d
  const int t = threadIdx.x;
  const int rr = t >> 4;          // 0..15
  const int cc = (t & 15) * 4;    // 0..60
  #pragma unroll
  for (int p = 0; p < 4; ++p) {
    const int row = p * 16 + rr;
    f32x4 v = *(const f32x4*)&src[batch + (size_t)(r0 + row) * L_ + c0 + cc];
    #pragma unroll
    for (int i = 0; i < 4; ++i) tile[(cc + i) * 65 + row] = v[i];
  }
  __syncthreads();
  const f32x4 wv = *(const f32x4*)&w[r0 + cc];
  #pragma unroll
  for (int p = 0; p < 4; ++p) {
    const int crow = p * 16 + rr;            // l offset within tile
    const int l = c0 + crow;
    const float scale = rsqrtf(ssq[(size_t)b * L_ + l] * (1.f / D_) + EPS_);
    bf16x4 o;
    #pragma unroll
    for (int i = 0; i < 4; ++i)
      o[i] = (short)f2bf(tile[crow * 65 + cc + i] * scale * wv[i]);
    *(bf16x4*)&mxn[((size_t)b * L_ + l) * D_ + r0 + cc] = o;
  }
}

// ---------------- MultiHeadEMA via chunked linear recurrence ----------------
// Round-13: coalesced writeback via padded LDS (obuf[64][33]).
// Round-15: REVERT round-14's __launch_bounds__(64,4) — the allocator
// collapsed to 64 VGPR (next occupancy granule below the 128 cap) and
// spilled the whole working set (measured: WRITE_SIZE 1.0 GB for a
// 64 MB output, dur 207 -> 440-480 us).  Plain (64) allocates 256 VGPR,
// no spill.  Do NOT re-add a min-waves bound here without verifying
// VGPR count via -Rpass-analysis first.
__global__ __launch_bounds__(64) void k_ema(const uint16_t* __restrict__ xnT,
                                            const float* __restrict__ delta,
                                            const float* __restrict__ alpha,
                                            const float* __restrict__ beta,
                                            const float* __restrict__ gamma,
                                            const float* __restrict__ omega,
                                            float* __restrict__ mxT) {
  __shared__ float hst[64 * NE_];
  __shared__ float obuf[64 * 33];   // padded: thread c owns row c (stride 33 ≡ 1 mod 32)
  const int bd = blockIdx.x;
  const int d = bd & (D_ - 1);
  const int c = threadIdx.x;

  float q[NE_], pb[NE_], gs[NE_];
  #pragma unroll
  for (int n = 0; n < NE_; ++n) {
    float p = sigmoidf_(delta[d * NE_ + n]);
    float a = sigmoidf_(alpha[d * NE_ + n]);
    q[n] = 1.f - p * a;
    pb[n] = p * beta[d * NE_ + n];
    gs[n] = gamma[d * NE_ + n] * 0.25f;
  }

  const uint16_t* xp = xnT + (size_t)bd * L_ + c * 32;
  bf16x8 xin[4];
  #pragma unroll
  for (int s = 0; s < 4; ++s) xin[s] = *(const bf16x8*)(xp + s * 8);

  float h[NE_];
  #pragma unroll
  for (int n = 0; n < NE_; ++n) h[n] = 0.f;

  #pragma unroll
  for (int k = 0; k < 32; ++k) {
    float xv = bf2f((uint16_t)xin[k >> 3][k & 7]);
    #pragma unroll
    for (int n = 0; n < NE_; ++n) h[n] = fmaf(q[n], h[n], pb[n] * xv);
  }
  #pragma unroll
  for (int n = 0; n < NE_; ++n) hst[c * NE_ + n] = h[n];
  __syncthreads();

  if (c < NE_) {
    float qq = q[c];
    float q32 = qq * qq; q32 *= q32; q32 *= q32; q32 *= q32; q32 *= q32;  // q^32
    float hi = 0.f;
    for (int cc = 0; cc < 64; ++cc) {
      float cur = hst[cc * NE_ + c];
      hst[cc * NE_ + c] = hi;
      hi = fmaf(q32, hi, cur);
    }
  }
  __syncthreads();

  #pragma unroll
  for (int n = 0; n < NE_; ++n) h[n] = hst[c * NE_ + n];
  const float om = omega[d];
  #pragma unroll
  for (int k = 0; k < 32; ++k) {
    float xv = bf2f((uint16_t)xin[k >> 3][k & 7]);
    float accv = 0.f;
    #pragma unroll
    for (int n = 0; n < NE_; ++n) {
      h[n] = fmaf(q[n], h[n], pb[n] * xv);
      accv = fmaf(gs[n], h[n], accv);
    }
    obuf[c * 33 + k] = accv + om * xv;
  }
  __syncthreads();
  // coalesced writeback: 8 x (64 lanes x 16 B contiguous)
  float* op = mxT + (size_t)bd * L_;
  #pragma unroll
  for (int p = 0; p < 8; ++p) {
    const int l = p * 256 + c * 4;
    const int row = l >> 5, col = l & 31;
    f32x4 v;
    #pragma unroll
    for (int i = 0; i < 4; ++i) v[i] = obuf[row * 33 + col + i];
    *(f32x4*)&op[l] = v;
  }
}

// ==================================================================
// 128x128-tile, BK=32, 4-wave, 2-phase prefetch GEMM, 4 blocks/CU.
// (~711 TF on BASE — round-10 structure, unchanged)
// ==================================================================

template <int MODE>
__global__ __launch_bounds__(256, 4) void k_gemm128(
    const uint16_t* __restrict__ A, const uint16_t* __restrict__ Bm,
    int N, int K,
    const float* __restrict__ bias,
    float* __restrict__ outf, uint16_t* __restrict__ outb,
    uint16_t* __restrict__ ubuf,
    uint16_t* __restrict__ rbuf, float* __restrict__ hxbuf,
    const float* __restrict__ x0,
    const float* __restrict__ qkg, const float* __restrict__ qkb,
    uint16_t* __restrict__ qbuf, uint16_t* __restrict__ kbuf) {
  __shared__ uint16_t sm[17408];  // 34.8 KiB: dbuf at 0/8192; epi transit reuses all
  const int t = threadIdx.x;
  const int lane = t & 63, wave = t >> 6;
  const int quad = lane >> 4, r16 = lane & 15;
  const int wm = wave >> 1, wn = wave & 1;
  const int bm = blockIdx.x * 128;
  const int bn = blockIdx.y * 128;

  f32x4 acc[4][4];
  const f32x4 zf = {0.f, 0.f, 0.f, 0.f};
  #pragma unroll
  for (int i = 0; i < 4; ++i)
    #pragma unroll
    for (int j = 0; j < 4; ++j) acc[i][j] = zf;

  const int sgz = (((t & 3) ^ ((t >> 3) & 3)) << 3);
  const uint16_t* gA = A + (size_t)(bm + (t >> 2)) * K + sgz;
  const uint16_t* gB = Bm + (size_t)(bn + (t >> 2)) * K + sgz;
  const size_t qstep = (size_t)64 * K;
  uint16_t* lA = sm + t * 8;
  uint16_t* lB = sm + 4096 + t * 8;

  const int ga = ((quad ^ ((r16 >> 1) & 3)) << 3);
  const int aOff = (wm * 64 + r16) * 32 + ga;
  const int bOff = 4096 + (wn * 64 + r16) * 32 + ga;

#define STAGE(c, kb) do {                                                     \
    gl2lds(gA + (kb), lA + (c) * 8192);                                       \
    gl2lds(gA + qstep + (kb), lA + (c) * 8192 + 2048);                        \
    gl2lds(gB + (kb), lB + (c) * 8192);                                       \
    gl2lds(gB + qstep + (kb), lB + (c) * 8192 + 2048);                        \
  } while (0)

  const int NT = K >> 5;

  STAGE(0, 0);
  __syncthreads();  // vmcnt(0) drain + barrier

  bf16x8 af[4], bfr[4];
  for (int tt = 0; tt < NT; ++tt) {
    const int c = tt & 1;
    const int co = c * 8192;
    if (tt + 1 < NT) STAGE(c ^ 1, (tt + 1) * 32);  // prefetch next tile
    #pragma unroll
    for (int j = 0; j < 4; ++j)
      bfr[j] = *(const bf16x8*)&sm[co + bOff + j * 512];
    #pragma unroll
    for (int i = 0; i < 4; ++i)
      af[i] = *(const bf16x8*)&sm[co + aOff + i * 512];
    #pragma unroll
    for (int i = 0; i < 4; ++i)
      #pragma unroll
      for (int j = 0; j < 4; ++j)
        acc[i][j] = __builtin_amdgcn_mfma_f32_16x16x32_bf16(
            af[i], bfr[j], acc[i][j], 0, 0, 0);
    __syncthreads();  // single vmcnt(0)+barrier per K-tile
  }
#undef STAGE

  // ---- epilogue ----
  if (MODE == 0) {
    #pragma unroll
    for (int i = 0; i < 4; ++i)
      #pragma unroll
      for (int j = 0; j < 4; ++j)
        #pragma unroll
        for (int r = 0; r < 4; ++r) {
          const int hloc = wn * 64 + j * 16 + r16;
          const int lloc = wm * 64 + i * 16 + quad * 4 + r;
          sm[hloc * 136 + lloc] = f2bf(siluf_(acc[i][j][r] + bias[bn + hloc]));
        }
    __syncthreads();
    const int bb = bm >> 11;            // batch index (tile never crosses)
    const int lb = bm & 2047;           // l offset within batch
    uint16_t* vTb = outb + (size_t)bb * H_ * L_;
    #pragma unroll
    for (int p = 0; p < 8; ++p) {
      const int hloc = p * 16 + (t >> 4);
      const int l0 = (t & 15) * 8;
      bf16x8 v = *(const bf16x8*)&sm[hloc * 136 + l0];
      *(bf16x8*)&vTb[(size_t)(bn + hloc) * L_ + lb + l0] = v;
    }
  } else if (MODE == 1) {
    const int rt = bn >> 7;   // 0-7 u | 8 q/k | 9-24 r | 25-32 hx
    if (rt >= 25) {
      #pragma unroll
      for (int i = 0; i < 4; ++i)
        #pragma unroll
        for (int j = 0; j < 4; ++j)
          #pragma unroll
          for (int r = 0; r < 4; ++r) {
            const int row = bm + wm * 64 + i * 16 + quad * 4 + r;
            const int col = bn + wn * 64 + j * 16 + r16;
            hxbuf[(size_t)row * D_ + (col - D_ - Z_ - H_)] = acc[i][j][r] + bias[col];
          }
    } else if (rt == 8) {
      #pragma unroll
      for (int pass = 0; pass < 2; ++pass) {
        #pragma unroll
        for (int i = 0; i < 4; ++i)
          #pragma unroll
          for (int j = 0; j < 4; ++j)
            #pragma unroll
            for (int r = 0; r < 4; ++r) {
              const int rowloc = wm * 64 + i * 16 + quad * 4 + r;
              const int zc = wn * 64 + j * 16 + r16;
              const float zv = siluf_(acc[i][j][r] + bias[D_ + zc]);
              const float o = pass == 0
                  ? (zv * qkg[zc] + qkb[zc]) * 0.08838834764831845f
                  : zv * qkg[Z_ + zc] + qkb[Z_ + zc];
              sm[rowloc * 136 + zc] = f2bf(o);
            }
        __syncthreads();
        uint16_t* dstb = pass == 0 ? qbuf : kbuf;
        #pragma unroll
        for (int p = 0; p < 8; ++p) {
          const int row = p * 16 + (t >> 4);
          const int c0 = (t & 15) * 8;
          bf16x8 v = *(const bf16x8*)&sm[row * 136 + c0];
          *(bf16x8*)&dstb[(size_t)(bm + row) * Z_ + c0] = v;
        }
        __syncthreads();
      }
    } else {
      const bool isU = rt < 8;
      #pragma unroll
      for (int i = 0; i < 4; ++i)
        #pragma unroll
        for (int j = 0; j < 4; ++j)
          #pragma unroll
          for (int r = 0; r < 4; ++r) {
            const int rowloc = wm * 64 + i * 16 + quad * 4 + r;
            const int colloc = wn * 64 + j * 16 + r16;
            const float val = acc[i][j][r] + bias[bn + colloc];
            sm[rowloc * 136 + colloc] = f2bf(isU ? sigmoidf_(val) : siluf_(val));
          }
      __syncthreads();
      #pragma unroll
      for (int p = 0; p < 8; ++p) {
        const int row = p * 16 + (t >> 4);
        const int c0 = (t & 15) * 8;
        bf16x8 v = *(const bf16x8*)&sm[row * 136 + c0];
        if (isU)
          *(bf16x8*)&ubuf[(size_t)(bm + row) * D_ + bn + c0] = v;
        else
          *(bf16x8*)&rbuf[(size_t)(bm + row) * H_ + (bn - D_ - Z_) + c0] = v;
      }
    }
  } else {
    #pragma unroll
    for (int i = 0; i < 4; ++i) {
      #pragma unroll
      for (int j = 0; j < 4; ++j) {
        #pragma unroll
        for (int r = 0; r < 4; ++r) {
          const int row = bm + wm * 64 + i * 16 + quad * 4 + r;
          const int col = bn + wn * 64 + j * 16 + r16;
          const size_t idx = (size_t)row * N + col;
          float g = siluf_(acc[i][j][r] + hxbuf[idx]);   // read hx (d_out) ...
          float xv = x0[idx];
          outf[idx] = xv + bf2f(ubuf[idx]) * (g - xv);  // ... then write same addr
        }
      }
    }
  }
}

// ---- fused QK^T + rel_bias + causal softmax -> packed-triangular P (bf16) ----
// K/relwin staging double-buffered with prefetch (1 barrier/kt).
__global__ __launch_bounds__(256) void k_qksm(
    const uint16_t* __restrict__ qg, const uint16_t* __restrict__ kg,
    const float* __restrict__ relb, uint16_t* __restrict__ Pp) {
  __shared__ uint16_t Ks[2 * 16384];
  __shared__ float relwin[2 * 256];
  const int qt = blockIdx.x;
  const int bl = blockIdx.y;
  const int tid = threadIdx.x;
  const int w = tid >> 6, lane = tid & 63;
  const int quad = lane >> 4, r16 = lane & 15;
  const uint16_t* qb_b = qg + (size_t)bl * L_ * Z_;
  const uint16_t* kb_b = kg + (size_t)bl * L_ * Z_;
  uint16_t* P_b = Pp + (size_t)bl * NPACK_ * TILE_ELEMS_;

  const int ksg = (tid >> 4) * 128 + (((tid & 15) ^ ((tid >> 4) & 7)) << 3);
  const int kg7 = r16 & 7;

#define STGK(c, kt) do {                                                      \
    const uint16_t* src_ = kb_b + (size_t)(kt) * 128 * Z_;                    \
    _Pragma("unroll")                                                         \
    for (int s2 = 0; s2 < 8; ++s2)                                            \
      gl2lds(src_ + s2 * 2048 + ksg, Ks + (c) * 16384 + s2 * 2048 + tid * 8); \
    if (tid < 255)                                                            \
      relwin[(c) * 256 + tid] = relb[2047 + ((kt) - qt) * 128 - 127 + tid];   \
  } while (0)

  bf16x8 aq[2][4];
  #pragma unroll
  for (int i = 0; i < 2; ++i)
    #pragma unroll
    for (int s = 0; s < 4; ++s)
      aq[i][s] = *(const bf16x8*)&qb_b[(size_t)(qt * 128 + w * 32 + i * 16 + r16) * Z_ +
                                       s * 32 + quad * 8];

  float m8[8], l8[8];
  #pragma unroll
  for (int t = 0; t < 8; ++t) { m8[t] = -3.4e38f; l8[t] = 0.f; }

  const f32x4 zf = {0.f, 0.f, 0.f, 0.f};

  // ---- phase 1: stats ----
  STGK(0, 0);
  __syncthreads();
  for (int kt = 0; kt <= qt; ++kt) {
    const int cur = kt & 1;
    if (kt < qt) STGK(cur ^ 1, kt + 1);
    const uint16_t* Kc = Ks + cur * 16384;
    const float* rw = relwin + cur * 256;
    #pragma unroll
    for (int j = 0; j < 8; ++j) {
      f32x4 a0 = zf, a1 = zf;
      #pragma unroll
      for (int s = 0; s < 4; ++s) {
        bf16x8 bk = *(const bf16x8*)&Kc[(j * 16 + r16) * 128 +
                                        (((s * 4 + quad) ^ kg7) << 3)];
        a0 = __builtin_amdgcn_mfma_f32_16x16x32_bf16(aq[0][s], bk, a0, 0, 0, 0);
        a1 = __builtin_amdgcn_mfma_f32_16x16x32_bf16(aq[1][s], bk, a1, 0, 0, 0);
      }
      #pragma unroll
      for (int i = 0; i < 2; ++i) {
        const f32x4 av = i ? a1 : a0;
        #pragma unroll
        for (int r = 0; r < 4; ++r) {
          const int rloc = w * 32 + i * 16 + quad * 4 + r;
          const int cloc = j * 16 + r16;
          if (kt < qt || cloc <= rloc) {
            const float v = av[r] + rw[cloc - rloc + 127];
            const int t = i * 4 + r;
            const float mn = fmaxf(m8[t], v);
            l8[t] = l8[t] * __expf(m8[t] - mn) + __expf(v - mn);
            m8[t] = mn;
          }
        }
      }
    }
    __syncthreads();
  }

  #pragma unroll
  for (int t = 0; t < 8; ++t) {
    #pragma unroll
    for (int msk = 1; msk <= 8; msk <<= 1) {
      const float mo = __shfl_xor(m8[t], msk, 64);
      const float lo = __shfl_xor(l8[t], msk, 64);
      const float mn = fmaxf(m8[t], mo);
      l8[t] = l8[t] * __expf(m8[t] - mn) + lo * __expf(mo - mn);
      m8[t] = mn;
    }
    l8[t] = 1.f / l8[t];
  }

  // ---- phase 2: recompute, normalize, write packed P ----
  STGK(0, 0);
  __syncthreads();
  for (int kt = 0; kt <= qt; ++kt) {
    const int cur = kt & 1;
    if (kt < qt) STGK(cur ^ 1, kt + 1);
    const uint16_t* Kc = Ks + cur * 16384;
    const float* rw = relwin + cur * 256;
    uint16_t* Pt = P_b + (size_t)(qt * (qt + 1) / 2 + kt) * TILE_ELEMS_;
    #pragma unroll
    for (int j = 0; j < 8; ++j) {
      f32x4 a0 = zf, a1 = zf;
      #pragma unroll
      for (int s = 0; s < 4; ++s) {
        bf16x8 bk = *(const bf16x8*)&Kc[(j * 16 + r16) * 128 +
                                        (((s * 4 + quad) ^ kg7) << 3)];
        a0 = __builtin_amdgcn_mfma_f32_16x16x32_bf16(aq[0][s], bk, a0, 0, 0, 0);
        a1 = __builtin_amdgcn_mfma_f32_16x16x32_bf16(aq[1][s], bk, a1, 0, 0, 0);
      }
      #pragma unroll
      for (int i = 0; i < 2; ++i) {
        const f32x4 av = i ? a1 : a0;
        #pragma unroll
        for (int r = 0; r < 4; ++r) {
          const int rloc = w * 32 + i * 16 + quad * 4 + r;
          const int cloc = j * 16 + r16;
          const int t = i * 4 + r;
          float p = 0.f;
          if (kt < qt || cloc <= rloc) {
            const float v = av[r] + rw[cloc - rloc + 127];
            p = __expf(v - m8[t]) * l8[t];
          }
          Pt[rloc * 128 + cloc] = f2bf(p);
        }
      }
    }
    __syncthreads();
  }
#undef STGK
}

// ---- PV GEMM: hr = (P @ V) * r, packed-triangular P, in-place over r ----
// 128x256 tile, 8 waves, BK=32 dbuf prefetch, 48 KiB LDS, (512,4).
__global__ __launch_bounds__(512, 4) void k_pv(
    const uint16_t* __restrict__ Pp, const uint16_t* __restrict__ vT,
    uint16_t* __restrict__ rh) {
  __shared__ uint16_t sm[24576];  // 48 KiB: buf c at c*12288; A(4096) +0, B(8192) +4096
  const int qt = NTILE_ - 1 - blockIdx.x;   // heavy blocks first
  const int bn = blockIdx.y * 256;
  const int bl = blockIdx.z;
  const uint16_t* Pq = Pp + (size_t)bl * NPACK_ * TILE_ELEMS_ +
                       (size_t)(qt * (qt + 1) / 2) * TILE_ELEMS_;
  const uint16_t* v_b = vT + (size_t)bl * H_ * L_;
  uint16_t* rh_b = rh + (size_t)bl * L_ * H_;

  const int tid = threadIdx.x;
  const int wave = tid >> 6, lane = tid & 63;
  const int quad = lane >> 4, r16 = lane & 15;
  const int wm = wave >> 2, wn = wave & 3;
  const int rowW = wm * 64, colW = wn * 64;

  f32x4 acc[4][4];
  const f32x4 zf = {0.f, 0.f, 0.f, 0.f};
  #pragma unroll
  for (int i = 0; i < 4; ++i)
    #pragma unroll
    for (int j = 0; j < 4; ++j) acc[i][j] = zf;

  const int rA = tid >> 2;   // 0..127
  const int sg = (((tid & 3) ^ ((tid >> 3) & 3)) << 3);
  const int gpv = ((quad ^ ((r16 >> 1) & 3)) << 3);

#define PVSTAGE(c, s) do {                                                    \
    const int kt_ = (s) >> 2, ks_ = (s) & 3;                                  \
    gl2lds(Pq + (size_t)kt_ * TILE_ELEMS_ + rA * 128 + ks_ * 32 + sg,         \
           sm + (c) * 12288 + tid * 8);                                       \
    const uint16_t* Bt_ = v_b + (size_t)(bn + rA) * L_ + kt_ * 128 +          \
                          ks_ * 32 + sg;                                      \
    gl2lds(Bt_, sm + (c) * 12288 + 4096 + tid * 8);                           \
    gl2lds(Bt_ + (size_t)128 * L_, sm + (c) * 12288 + 8192 + tid * 8);        \
  } while (0)

  const int S = 4 * (qt + 1);

  PVSTAGE(0, 0);
  __syncthreads();

  bf16x8 af[4], bfr[4];
  for (int s = 0; s < S; ++s) {
    const int c = s & 1;
    const int co = c * 12288;
    if (s + 1 < S) PVSTAGE(c ^ 1, s + 1);
    #pragma unroll
    for (int j = 0; j < 4; ++j)
      bfr[j] = *(const bf16x8*)&sm[co + 4096 + (colW + j * 16 + r16) * 32 + gpv];
    #pragma unroll
    for (int i = 0; i < 4; ++i)
      af[i] = *(const bf16x8*)&sm[co + (rowW + i * 16 + r16) * 32 + gpv];
    #pragma unroll
    for (int i = 0; i < 4; ++i)
      #pragma unroll
      for (int j = 0; j < 4; ++j)
        acc[i][j] = __builtin_amdgcn_mfma_f32_16x16x32_bf16(af[i], bfr[j], acc[i][j], 0, 0, 0);
    __syncthreads();
  }
#undef PVSTAGE

  #pragma unroll
  for (int i = 0; i < 4; ++i) {
    #pragma unroll
    for (int j = 0; j < 4; ++j) {
      #pragma unroll
      for (int r = 0; r < 4; ++r) {
        const int row = qt * 128 + rowW + i * 16 + quad * 4 + r;
        const int col = bn + colW + j * 16 + r16;
        const size_t idx = (size_t)row * H_ + col;
        const float rv = bf2f(rh_b[idx]);
        rh_b[idx] = f2bf(acc[i][j][r] * rv);
      }
    }
  }
}

extern "C" void kernel_launch(void* const* d_in, const int* in_sizes, int n_in,
                              void* d_out, int out_size, void* d_ws, size_t ws_size,
                              hipStream_t stream) {
  (void)in_sizes; (void)n_in;
  const float* x         = (const float*)d_in[0];
  const float* prior_mean= (const float*)d_in[1];
  const float* prior_logv= (const float*)d_in[2];
  const float* tn_w      = (const float*)d_in[3];
  const float* tn_b      = (const float*)d_in[4];
  const float* delta     = (const float*)d_in[5];
  const float* alpha     = (const float*)d_in[6];
  const float* ema_beta  = (const float*)d_in[7];
  const float* ema_gamma = (const float*)d_in[8];
  const float* omega     = (const float*)d_in[9];
  const float* rms_w     = (const float*)d_in[10];
  const float* Wv        = (const float*)d_in[11];
  const float* bv        = (const float*)d_in[12];
  const float* Wmx       = (const float*)d_in[13];
  const float* bmx       = (const float*)d_in[14];
  const float* Wh        = (const float*)d_in[15];
  const float* qk_gamma  = (const float*)d_in[16];
  const float* qk_beta   = (const float*)d_in[17];
  const float* rel_bias  = (const float*)d_in[18];
  float* out = (float*)d_out;

  const int BL = B_ * L_;
  const size_t MB = 1024 * 1024;
  const size_t REQUIRED = 256 * MB;

  if (ws_size < REQUIRED) {
    k_fallback<<<dim3(4096), dim3(256), 0, stream>>>(out, out_size, (float)(ws_size / MB));
    return;
  }

  char* p = (char*)d_ws;
  // A [0,32): xn (bf16) -> ubuf (bf16)
  uint16_t* xn   = (uint16_t*)(p);
  uint16_t* ubuf = (uint16_t*)(p);
  // B [32,64): xnT (live steps 2-4) -> mxn (live 5-7)
  uint16_t* xnT  = (uint16_t*)(p + 32 * MB);
  uint16_t* mxn  = (uint16_t*)(p + 32 * MB);
  // C [64,128): vT (64 MiB exactly; written by V GEMM, read by k_pv)
  uint16_t* vT   = (uint16_t*)(p + 64 * MB);
  // D [128,192): wv_b [128,132) steps 1-3 | s1g/s2g [132,136) step 2 |
  //              ssq [136,137) step 5 | rbuf/hr (7-11, from 128)
  uint16_t* wv_b = (uint16_t*)(p + 128 * MB);
  float*    s1g  = (float*)   (p + 132 * MB);
  float*    s2g  = (float*)   (p + 134 * MB);
  float*    ssq  = (float*)   (p + 136 * MB);
  uint16_t* rbuf = (uint16_t*)(p + 128 * MB);
  // E [192,256): wmx_b(8.25) | qb(4) | kb(4) | Ppack(35.65)
  uint16_t* wmx_b = (uint16_t*)(p + 192 * MB);
  uint16_t* wh_b  = (uint16_t*)(p + 192 * MB);
  uint16_t* qb    = (uint16_t*)(p + 209 * MB);
  uint16_t* kb2   = (uint16_t*)(p + 213 * MB);
  uint16_t* Ppack = (uint16_t*)(p + 217 * MB);
  // d_out doubles as: mxT f32 (EMA out) -> hx f32 (BASE out) -> out
  float* mxT = out;
  float* hx  = out;

  // 1. weights -> bf16
  k_f2bf<<<dim3(1024), dim3(256), 0, stream>>>(Wv, wv_b, H_ * D_);
  k_f2bf<<<dim3(2048), dim3(256), 0, stream>>>(Wmx, wmx_b, NMX_ * D_);
  // 2. timestep norm (3-phase parallel) -> xn AND xnT (fused transpose)
  k_tnsum<<<dim3(B_ * G_, 16), dim3(256), 0, stream>>>(x, s1g, s2g);
  k_tnscan<<<dim3(B_ * G_), dim3(64), 0, stream>>>(s1g, s2g);
  k_tnnorm<<<dim3(B_ * G_, 16), dim3(256), 0, stream>>>(
      x, s1g, s2g, prior_mean, prior_logv, tn_w, tn_b, xn, xnT);
  // 3. v = silu(xn @ Wv^T + bv), written TRANSPOSED -> vT (C)
  k_gemm128<0><<<dim3(BL / 128, H_ / 128), dim3(256), 0, stream>>>(
      xn, wv_b, H_, D_, bv, nullptr, vT,
      nullptr, nullptr, nullptr, nullptr, nullptr, nullptr, nullptr, nullptr);
  // 4. EMA: xnT -> mxT (d_out), coalesced writeback
  k_ema<<<dim3(B_ * D_), dim3(64), 0, stream>>>(xnT, delta, alpha, ema_beta, ema_gamma, omega, mxT);
  // 5. RMS directly from mxT: sumsq, then fused transpose+scale -> mxn
  k_mssq<<<dim3(L_ / 64, B_), dim3(256), 0, stream>>>(mxT, ssq);
  k_tprms<<<dim3(L_ / 64, D_ / 64, B_), dim3(256), 0, stream>>>(mxT, ssq, rms_w, mxn);
  // 7. BASE GEMM -> u(A), q/k(E, fused qkprep), r(D), hx(d_out)
  k_gemm128<1><<<dim3(BL / 128, NMX_ / 128), dim3(256), 0, stream>>>(
      mxn, wmx_b, NMX_, D_, bmx, nullptr, nullptr,
      ubuf, rbuf, hx, nullptr, qk_gamma, qk_beta, qb, kb2);
  // 8. fused QK+softmax -> packed P (all 8 batches, one dispatch)
  k_qksm<<<dim3(NTILE_, B_), dim3(256), 0, stream>>>(qb, kb2, rel_bias, Ppack);
  // 9. PV GEMM, hr = (P@V)*r in-place over rbuf (one dispatch)
  k_pv<<<dim3(NTILE_, H_ / 256, B_), dim3(512), 0, stream>>>(Ppack, vT, rbuf);
  // 10. Wh -> bf16 (over dead wmx_b)
  k_f2bf<<<dim3(1024), dim3(256), 0, stream>>>(Wh, wh_b, D_ * H_);
  // 11. final: g = silu(hx + hr@Wh^T); out = x + u*(g-x)
  k_gemm128<4><<<dim3(BL / 128, D_ / 128), dim3(256), 0, stream>>>(
      rbuf, wh_b, D_, H_, nullptr, out, nullptr,
      ubuf, nullptr, hx, x, nullptr, nullptr, nullptr, nullptr);
}